// Round 3
// baseline (4472.328 us; speedup 1.0000x reference)
//
#include <hip/hip_runtime.h>
#include <math.h>

// Shapes (fixed): B=16, Cin=3, C=64, H=W=384, E=768, P=16, G=24, K_sel=64
// conv2: no-LDS direct-operand MFMA (split-2 bf16, 3 terms), padded f1 (386x386 NHWC)
//        v3: 1-wave blocks, depth-2 A prefetch (3 bufs) + depth-1 B (2 bufs), static
//        18-step unroll, setprio around MFMA; XCD-aligned producer/consumer swizzles.
// coarse: M=576,N=768,K=16384  detail(sel): M=256,N=768,K=4096  merge: M=1024,N=768,K=3072

__device__ __forceinline__ float gelu_f(float v){
    return 0.5f*v*(1.0f + erff(v*0.70710678118654752440f));
}
__device__ __forceinline__ unsigned short f2bf(float v){
    unsigned u = __float_as_uint(v);
    return (unsigned short)((u + 0x7FFFu + ((u>>16)&1u)) >> 16);   // RNE
}
__device__ __forceinline__ float bf2f(unsigned short h){
    return __uint_as_float(((unsigned)h)<<16);
}
__device__ __forceinline__ void split2(float v, unsigned short& hi, unsigned short& lo){
    hi = f2bf(v);
    lo = f2bf(v - bf2f(hi));
}

typedef short bf16x8 __attribute__((ext_vector_type(8)));
typedef float f32x4  __attribute__((ext_vector_type(4)));

// ---- BN scale/shift: out[0..63]=s1, [64..127]=sh1, [128..191]=s2, [192..255]=sh2
__global__ void bnprep_k(const float* g1,const float* b1,const float* m1,const float* v1,
                         const float* g2,const float* b2,const float* m2,const float* v2,
                         float* outp){
    int t = threadIdx.x;
    if (t < 64){
        float s = g1[t]/sqrtf(v1[t]+1e-5f);
        outp[t] = s; outp[64+t] = b1[t]-m1[t]*s;
        float s2 = g2[t]/sqrtf(v2[t]+1e-5f);
        outp[128+t] = s2; outp[192+t] = b2[t]-m2[t]*s2;
    }
}

// ---- conv2 weights -> split-2 bf16, n-major [64][576], k' = (kh*3+kw)*64 + ci
__global__ void w2prep_k(const float* __restrict__ w,
                         unsigned short* __restrict__ bhi, unsigned short* __restrict__ blo){
    int idx = blockIdx.x*256 + threadIdx.x;
    if (idx >= 36864) return;
    int n = idx/576, kp = idx - n*576;
    int t = kp>>6, ci = kp&63; int kh = t/3, kw = t - kh*3;
    float v = w[((n*64+ci)*3+kh)*3+kw];
    unsigned short hi,lo; split2(v,hi,lo);
    bhi[n*576+kp]=hi; blo[n*576+kp]=lo;
}

// ---- flat f32 -> bf16 convert
__global__ __launch_bounds__(256) void cvtbf16_k(const float* __restrict__ in,
                                                 unsigned short* __restrict__ out, int n){
    int i = blockIdx.x*256 + threadIdx.x;
    if (i < n) out[i] = f2bf(in[i]);
}

// ---- zero the 1-px border of padded f1 (386x386x64), hi+lo; run once
__global__ __launch_bounds__(256) void zpad_k(unsigned short* __restrict__ f1hi,
                                              unsigned short* __restrict__ f1lo){
    int idx = blockIdx.x*256 + threadIdx.x;
    if (idx >= 1540*8) return;
    int pi = idx>>3, c8 = (idx&7)*8;
    int p;
    if (pi < 386)       p = pi;                       // top row
    else if (pi < 772)  p = 385*386 + (pi-386);       // bottom row
    else if (pi < 1156) p = (pi-772+1)*386;           // left col rows 1..384
    else                p = (pi-1156+1)*386 + 385;    // right col rows 1..384
    float4 z = {0.f,0.f,0.f,0.f};
    *(float4*)(f1hi + (size_t)p*64 + c8) = z;
    *(float4*)(f1lo + (size_t)p*64 + c8) = z;
}

// ---- conv1 3->64 3x3 SAME + BN + GELU; padded (386x386) NHWC split-2 bf16 (one image)
// Block swizzle XCD-aligned with conv2's reader: pixels [18432*x,18432*(x+1)) on XCD x.
__global__ __launch_bounds__(256) void conv1_k(const float* __restrict__ x,
                                               const float* __restrict__ w,
                                               const float* __restrict__ bnp,
                                               unsigned short* __restrict__ f1hi,
                                               unsigned short* __restrict__ f1lo){
    __shared__ float ws[64*27];
    __shared__ float xr[32*28];
    __shared__ float s1[64], sh1[64];
    int tid = threadIdx.x;
    for (int i=tid;i<1728;i+=256) ws[i] = w[i];
    if (tid < 64){ s1[tid] = bnp[tid]; sh1[tid] = bnp[64+tid]; }
    int px = tid>>3, cg = tid&7;
    int bid = blockIdx.x;
    int swb = (bid&7)*576 + (bid>>3);      // 4608 blocks, XCD-aligned
    int p = swb*32 + px;                   // pixel
    int h = p/384, wq = p - h*384;
    for (int j=cg; j<27; j+=8){
        int ci = j/9, t9 = j - ci*9; int kh = t9/3, kw = t9 - kh*3;
        int y = h+kh-1, xx = wq+kw-1;
        float v = 0.f;
        if ((unsigned)y<384u && (unsigned)xx<384u)
            v = x[ci*147456 + y*384 + xx];
        xr[px*28+j] = v;
    }
    __syncthreads();
    float a[8];
    #pragma unroll
    for (int u=0;u<8;u++) a[u]=0.f;
    #pragma unroll
    for (int j=0;j<27;j++){
        float xv = xr[px*28+j];
        #pragma unroll
        for (int u=0;u<8;u++) a[u] += xv*ws[(cg*8+u)*27+j];
    }
    unsigned short hs[8], ls[8];
    #pragma unroll
    for (int u=0;u<8;u++){
        int co = cg*8+u;
        float v = gelu_f(a[u]*s1[co] + sh1[co]);
        split2(v, hs[u], ls[u]);
    }
    size_t off = ((size_t)(h+1)*386 + (wq+1))*64 + cg*8;
    *(float4*)(f1hi + off) = *(float4*)hs;
    *(float4*)(f1lo + off) = *(float4*)ls;
}

// ---- conv2 via split-2 bf16 MFMA, NO LDS, 1 wave/block (64x64 tile), 2304 blocks.
// 18 steps s=(t9,h); A prefetched 2 steps ahead (3 rotating buffers), B 1 step (2 bufs).
// Static unroll -> all buffer indices compile-time; WAR deps enforce pipeline depth.
// fb output is PIXEL-major: fb[p*64 + n].
#define AO_(s) ((((s)>>1)/3)*386*64 + (((s)>>1)%3)*64 + ((s)&1)*32)
#define BO_(s) (((s)>>1)*64 + ((s)&1)*32)

#define LOAD_A(buf, s) { \
    _Pragma("unroll") for (int mi_=0;mi_<4;mi_++){ \
        Ah[buf][mi_] = *(const bf16x8*)(f1hi + pb[mi_] + AO_(s)); \
        Al[buf][mi_] = *(const bf16x8*)(f1lo + pb[mi_] + AO_(s)); } }

#define LOAD_B(buf, s) { \
    _Pragma("unroll") for (int nj_=0;nj_<4;nj_++){ \
        Bh[buf][nj_] = *(const bf16x8*)(bhi + nb + nj_*9216 + BO_(s)); \
        Bl[buf][nj_] = *(const bf16x8*)(blo + nb + nj_*9216 + BO_(s)); } }

__global__ __launch_bounds__(64) void conv2_mfma_k(
        const unsigned short* __restrict__ f1hi, const unsigned short* __restrict__ f1lo,
        const unsigned short* __restrict__ bhi,  const unsigned short* __restrict__ blo,
        const float* __restrict__ bnsc, const float* __restrict__ bnsh,
        float* __restrict__ fb){
    const int lane = threadIdx.x, lm = lane&15, q = lane>>4;
    const int bid = blockIdx.x;
    const int swz = (bid&7)*288 + (bid>>3);       // 2304 blocks, 8 XCDs, bijective
    const int bm = swz*64;

    // per-mi base address (shorts) of this lane's pixel in padded f1
    int pb[4];
    #pragma unroll
    for (int mi=0;mi<4;mi++){
        int p = bm + mi*16 + lm;
        int y = p/384, x = p - y*384;
        pb[mi] = (y*386 + x)*64 + q*8;
    }
    const int nb = lm*576 + q*8;

    f32x4 acc[4][4];
    #pragma unroll
    for (int i=0;i<4;i++)
        #pragma unroll
        for (int j=0;j<4;j++) acc[i][j] = (f32x4){0.f,0.f,0.f,0.f};

    bf16x8 Ah[3][4], Al[3][4], Bh[2][4], Bl[2][4];

    LOAD_A(0, 0);
    LOAD_A(1, 1);
    LOAD_B(0, 0);

    #pragma unroll
    for (int s=0;s<18;s++){
        if (s < 16) LOAD_A((s+2)%3, s+2);
        if (s < 17) LOAD_B((s+1)&1, s+1);
        __builtin_amdgcn_s_setprio(1);
        #pragma unroll
        for (int mi=0;mi<4;mi++)
            #pragma unroll
            for (int nj=0;nj<4;nj++){
                acc[mi][nj] = __builtin_amdgcn_mfma_f32_16x16x32_bf16(Ah[s%3][mi], Bh[s&1][nj], acc[mi][nj], 0,0,0);
                acc[mi][nj] = __builtin_amdgcn_mfma_f32_16x16x32_bf16(Al[s%3][mi], Bh[s&1][nj], acc[mi][nj], 0,0,0);
                acc[mi][nj] = __builtin_amdgcn_mfma_f32_16x16x32_bf16(Ah[s%3][mi], Bl[s&1][nj], acc[mi][nj], 0,0,0);
            }
        __builtin_amdgcn_s_setprio(0);
    }

    #pragma unroll
    for (int nj=0;nj<4;nj++){
        const int n = nj*16 + lm;
        const float sc = bnsc[n], sh = bnsh[n];
        #pragma unroll
        for (int mi=0;mi<4;mi++){
            const int m0 = bm + mi*16 + q*4;
            #pragma unroll
            for (int r=0;r<4;r++)
                fb[(size_t)(m0+r)*64 + n] = gelu_f(acc[mi][nj][r]*sc + sh);
        }
    }
}

// ---- fused variance-score + coarse patchify (one batch): block = one cell
// Cell swizzle XCD-aligned with conv2's fb writer (cell row gy -> XCD gy/3).
// fb is pixel-major; transpose via LDS (stride 257). Variance summation order
// kept identical (j*16+part + shuffle tree) for bit-stable scores.
__global__ __launch_bounds__(256) void varpatch_k(const float* __restrict__ fb,
                                                  float* __restrict__ scores,
                                                  unsigned short* __restrict__ Ac){
    __shared__ float buf[16*257];
    __shared__ float var_s[64];
    const int bid0 = blockIdx.x;          // 0..575
    const int bid = (bid0&7)*72 + (bid0>>3);   // cell, XCD-aligned
    const int gy = bid/24, gx = bid - gy*24;
    const int tid = threadIdx.x;
    const int cl = tid>>4, part = tid&15;
    const int pixbase = gy*16*384 + gx*16;
    unsigned short* acbase = Ac + (size_t)bid*16384;
    for (int cb=0; cb<4; cb++){
        #pragma unroll
        for (int i=0;i<4;i++){
            int idx = i*256 + tid;          // 0..1023 float4s
            int p = idx>>2, c4 = idx&3;
            int py = p>>4, px = p&15;
            const float4 v = *(const float4*)(fb + (size_t)(pixbase + py*384 + px)*64 + cb*16 + c4*4);
            buf[(c4*4+0)*257 + p] = v.x;
            buf[(c4*4+1)*257 + p] = v.y;
            buf[(c4*4+2)*257 + p] = v.z;
            buf[(c4*4+3)*257 + p] = v.w;
        }
        __syncthreads();
        float s = 0.f;
        #pragma unroll
        for (int j=0;j<16;j++) s += buf[cl*257 + j*16 + part];
        s += __shfl_down(s,8,16); s += __shfl_down(s,4,16);
        s += __shfl_down(s,2,16); s += __shfl_down(s,1,16);
        float mean = __shfl(s,0,16) * (1.f/256.f);
        float qv = 0.f;
        #pragma unroll
        for (int j=0;j<16;j++){ float d = buf[cl*257 + j*16 + part] - mean; qv += d*d; }
        qv += __shfl_down(qv,8,16); qv += __shfl_down(qv,4,16);
        qv += __shfl_down(qv,2,16); qv += __shfl_down(qv,1,16);
        if (part==0) var_s[cb*16+cl] = qv*(1.f/256.f);
        // Ac16: channel-major (k = c*256 + py*16 + px), coalesced ushort2 stores
        #pragma unroll
        for (int i=0;i<8;i++){
            int e2 = i*256 + tid;            // 0..2047
            int c16 = e2>>7, p2 = (e2&127)*2;
            unsigned int u = (unsigned)f2bf(buf[c16*257 + p2]) |
                             ((unsigned)f2bf(buf[c16*257 + p2+1])<<16);
            *(unsigned int*)(acbase + (cb*16+c16)*256 + p2) = u;
        }
        __syncthreads();
    }
    if (tid==0){
        float a=0.f;
        for (int c=0;c<64;c++) a += var_s[c];
        scores[bid] = a*(1.f/64.f);
    }
}

// ---- generic bf16 MFMA GEMM: tile M=64 x N=128, 256 thr (4 waves), K-split z
// MODE 0: coarse  A=Ac16 rows [576][16384]
// MODE 1: detail  A=Ac16 gathered: row=(topk[sel],dy,dx), k=c*64+qy*8+qx
// MODE 2: merge   A=dp16 rows [1024][3072]
template<int MODE, int KL, int MT>
__global__ __launch_bounds__(256) void gemm16_k(const unsigned short* __restrict__ A,
                                                const unsigned short* __restrict__ W,
                                                const int* __restrict__ topk,
                                                float* __restrict__ part){
    constexpr int KT = (MODE==0)?16384:(MODE==1)?4096:3072;   // W row length
    __shared__ __align__(16) unsigned short As[64*40];
    __shared__ __align__(16) unsigned short Bs[128*40];
    const int tid = threadIdx.x;
    const int nt = blockIdx.x, mt = blockIdx.y, z = blockIdx.z;
    const int m0 = mt*64, n0 = nt*128;
    const int wv = tid>>6, lane = tid&63;
    const int lm = lane&15, q = lane>>4;
    const int ar = tid>>2, ak = (tid&3)*8;

    size_t abase;
    if (MODE==1){
        int t = m0 + ar; int sel = t>>2, dd = t&3;
        int cell = topk[sel];
        abase = (size_t)cell*16384 + (dd>>1)*128 + (dd&1)*8;
    } else if (MODE==0){
        abase = (size_t)(m0+ar)*16384;
    } else {
        abase = (size_t)(m0+ar)*3072;
    }

    f32x4 acc[4][2];
    #pragma unroll
    for (int i=0;i<4;i++)
        #pragma unroll
        for (int j=0;j<2;j++)
            acc[i][j] = (f32x4){0.f,0.f,0.f,0.f};

    const int kb0 = z*KL;
    for (int kb = kb0; kb < kb0+KL; kb += 32){
        {
            int k0 = kb + ak;
            size_t src = (MODE==1) ? (abase + (k0>>6)*256 + ((k0>>3)&7)*16)
                                   : (abase + k0);
            const float4 v = *(const float4*)(A + src);
            *(float4*)(&As[ar*40 + ak]) = v;
        }
        #pragma unroll
        for (int i=0;i<2;i++){
            const float4 v = *(const float4*)(W + (size_t)(n0+ar+i*64)*KT + kb + ak);
            *(float4*)(&Bs[(ar+i*64)*40 + ak]) = v;
        }
        __syncthreads();
        bf16x8 af[4], bb[2];
        #pragma unroll
        for (int mi=0;mi<4;mi++) af[mi] = *(const bf16x8*)(&As[(mi*16+lm)*40 + q*8]);
        #pragma unroll
        for (int nj=0;nj<2;nj++) bb[nj] = *(const bf16x8*)(&Bs[(wv*32+nj*16+lm)*40 + q*8]);
        #pragma unroll
        for (int mi=0;mi<4;mi++)
            #pragma unroll
            for (int nj=0;nj<2;nj++)
                acc[mi][nj] = __builtin_amdgcn_mfma_f32_16x16x32_bf16(af[mi], bb[nj], acc[mi][nj], 0,0,0);
        __syncthreads();
    }

    float* pz = part + (size_t)z*MT*768;
    #pragma unroll
    for (int mi=0;mi<4;mi++)
        #pragma unroll
        for (int nj=0;nj<2;nj++)
            #pragma unroll
            for (int r=0;r<4;r++){
                int m = m0 + mi*16 + q*4 + r;
                int n = n0 + wv*32 + nj*16 + lm;
                pz[m*768 + n] = acc[mi][nj][r];
            }
}

// ---- sum K-split partials + bias -> f32
__global__ __launch_bounds__(256) void reduce_k(const float* __restrict__ partials,
                                                const float* __restrict__ bias,
                                                float* __restrict__ outp,
                                                int MTOT, int NSPLIT){
    int idx = blockIdx.x*256 + threadIdx.x;
    int col = idx % 768;
    float s = bias[col];
    for (int i=0;i<NSPLIT;i++) s += partials[(size_t)i*MTOT*768 + idx];
    outp[idx] = s;
}

// ---- sum K-split partials + bias -> bf16
__global__ __launch_bounds__(256) void reduce16_k(const float* __restrict__ partials,
                                                  const float* __restrict__ bias,
                                                  unsigned short* __restrict__ outp,
                                                  int MTOT, int NSPLIT){
    int idx = blockIdx.x*256 + threadIdx.x;
    int col = idx % 768;
    float s = bias[col];
    for (int i=0;i<NSPLIT;i++) s += partials[(size_t)i*MTOT*768 + idx];
    outp[idx] = f2bf(s);
}

// ---- top-64 of 576 via rank counting; jax tie-break (lower idx first), one shot
__global__ __launch_bounds__(576) void topk_k(const float* __restrict__ scores,
                                              int* __restrict__ topk,
                                              float* __restrict__ outf){
    __shared__ float s[576];
    int t = threadIdx.x;
    s[t] = scores[t];
    __syncthreads();
    float v = s[t];
    int cnt = 0;
    for (int j=0;j<576;j++){
        float u = s[j];
        cnt += (u > v) || (u == v && j < t);
    }
    if (cnt < 64){ topk[cnt] = t; outf[cnt] = (float)t; }
}

extern "C" void kernel_launch(void* const* d_in, const int* in_sizes, int n_in,
                              void* d_out, int out_size, void* d_ws, size_t ws_size,
                              hipStream_t stream){
    const float* x       = (const float*)d_in[0];
    const float* conv1_w = (const float*)d_in[1];
    const float* bn1_g   = (const float*)d_in[2];
    const float* bn1_b   = (const float*)d_in[3];
    const float* bn1_m   = (const float*)d_in[4];
    const float* bn1_v   = (const float*)d_in[5];
    const float* conv2_w = (const float*)d_in[6];
    const float* bn2_g   = (const float*)d_in[7];
    const float* bn2_b   = (const float*)d_in[8];
    const float* bn2_m   = (const float*)d_in[9];
    const float* bn2_v   = (const float*)d_in[10];
    const float* coarse_w= (const float*)d_in[11];
    const float* coarse_b= (const float*)d_in[12];
    const float* detail_w= (const float*)d_in[13];
    const float* detail_b= (const float*)d_in[14];
    const float* merge_w = (const float*)d_in[15];
    const float* merge_b = (const float*)d_in[16];
    float* out = (float*)d_out;

    // ---- workspace layout (float units); ~152 MB ----
    float* wsp  = (float*)d_ws;
    unsigned short* f1hi = (unsigned short*)wsp;         // 9,535,744 bf16 (386*386*64)
    unsigned short* f1lo = f1hi + 9535744;               // 9,535,744 bf16
    float* fb   = wsp + 9535744;                         // 9,437,184 f32 (pixel-major)
    float* bnp  = fb + 9437184;                          // 256
    float* scores = bnp + 256;                           // 9,216
    int*   topk = (int*)(scores + 9216);                 // 1,024
    unsigned short* B2hi = (unsigned short*)(topk + 1024);   // 36,864 bf16
    unsigned short* B2lo = B2hi + 36864;                     // 36,864 bf16
    unsigned short* Wc16 = B2lo + 36864;                     // 12,582,912 bf16
    unsigned short* Wd16 = Wc16 + 12582912;                  // 3,145,728 bf16
    unsigned short* Wm16 = Wd16 + 3145728;                   // 2,359,296 bf16
    unsigned short* Ac16 = Wm16 + 2359296;                   // 9,437,184 bf16
    unsigned short* dp16 = Ac16 + 9437184;                   // 3,145,728 bf16
    float* part = (float*)(dp16 + 3145728);                  // 3,538,944 f32

    if (ws_size < (size_t)171000000) return;   // graceful fail if ws too small

    const int DETAIL_OFF = 16*576*768;            // 7077888
    const int IDX_OFF    = DETAIL_OFF + 16*64*768;// 7864320

    bnprep_k<<<1,64,0,stream>>>(bn1_g,bn1_b,bn1_m,bn1_v, bn2_g,bn2_b,bn2_m,bn2_v, bnp);
    w2prep_k<<<144,256,0,stream>>>(conv2_w, B2hi, B2lo);
    cvtbf16_k<<<49152,256,0,stream>>>(coarse_w, Wc16, 12582912);
    cvtbf16_k<<<12288,256,0,stream>>>(detail_w, Wd16, 3145728);
    cvtbf16_k<<<9216,256,0,stream>>>(merge_w,  Wm16, 2359296);
    zpad_k<<<49,256,0,stream>>>(f1hi, f1lo);     // once: borders stay zero

    for (int b = 0; b < 16; b++){
        conv1_k<<<4608,256,0,stream>>>(x + (size_t)b*442368, conv1_w, bnp, f1hi, f1lo);
        conv2_mfma_k<<<2304,64,0,stream>>>(f1hi, f1lo, B2hi, B2lo, bnp+128, bnp+192, fb);
        varpatch_k<<<576,256,0,stream>>>(fb, scores + b*576, Ac16);
        topk_k<<<1,576,0,stream>>>(scores + b*576, topk + b*64, out + IDX_OFF + b*64);
        // coarse tokens
        gemm16_k<0,2048,576><<<dim3(6,9,8),256,0,stream>>>(Ac16, Wc16, nullptr, part);
        reduce_k<<<1728,256,0,stream>>>(part, coarse_b, out + (size_t)b*442368, 576, 8);
        // detail tokens (selected) — A gathered from Ac16
        gemm16_k<1,1024,256><<<dim3(6,4,4),256,0,stream>>>(Ac16, Wd16, topk + b*64, part);
        reduce16_k<<<768,256,0,stream>>>(part, detail_b, dp16 + (size_t)b*196608, 256, 4);
    }

    // merge over all batches: M=1024, K=3072
    gemm16_k<2,768,1024><<<dim3(6,16,4),256,0,stream>>>(dp16, Wm16, nullptr, part);
    reduce_k<<<3072,256,0,stream>>>(part, merge_b, out + DETAIL_OFF, 1024, 4);
}

// Round 4
// 3570.729 us; speedup vs baseline: 1.2525x; 1.2525x over previous
//
#include <hip/hip_runtime.h>
#include <math.h>

// Shapes (fixed): B=16, Cin=3, C=64, H=W=384, E=768, P=16, G=24, K_sel=64
// conv2: round-0 proven structure (192 thr, LDS-staged, 2 barriers/tap), padded f1
//        (unconditional staging), XCD-aligned swizzle, FUSED epilogue:
//        writes Ac16 bf16 + per-(cell,row,ch) {sum,sumsq} partials; fb eliminated.
// coarse: M=576,N=768,K=16384  detail(sel): M=256,N=768,K=4096  merge: M=1024,N=768,K=3072

__device__ __forceinline__ float gelu_f(float v){
    return 0.5f*v*(1.0f + erff(v*0.70710678118654752440f));
}
__device__ __forceinline__ unsigned short f2bf(float v){
    unsigned u = __float_as_uint(v);
    return (unsigned short)((u + 0x7FFFu + ((u>>16)&1u)) >> 16);   // RNE
}
__device__ __forceinline__ float bf2f(unsigned short h){
    return __uint_as_float(((unsigned)h)<<16);
}
__device__ __forceinline__ void split2(float v, unsigned short& hi, unsigned short& lo){
    hi = f2bf(v);
    lo = f2bf(v - bf2f(hi));
}

typedef short bf16x8 __attribute__((ext_vector_type(8)));
typedef float f32x4  __attribute__((ext_vector_type(4)));

// ---- BN scale/shift: out[0..63]=s1, [64..127]=sh1, [128..191]=s2, [192..255]=sh2
__global__ void bnprep_k(const float* g1,const float* b1,const float* m1,const float* v1,
                         const float* g2,const float* b2,const float* m2,const float* v2,
                         float* outp){
    int t = threadIdx.x;
    if (t < 64){
        float s = g1[t]/sqrtf(v1[t]+1e-5f);
        outp[t] = s; outp[64+t] = b1[t]-m1[t]*s;
        float s2 = g2[t]/sqrtf(v2[t]+1e-5f);
        outp[128+t] = s2; outp[192+t] = b2[t]-m2[t]*s2;
    }
}

// ---- conv2 weights -> split-2 bf16, n-major [64][576], k' = (kh*3+kw)*64 + ci
__global__ void w2prep_k(const float* __restrict__ w,
                         unsigned short* __restrict__ bhi, unsigned short* __restrict__ blo){
    int idx = blockIdx.x*256 + threadIdx.x;
    if (idx >= 36864) return;
    int n = idx/576, kp = idx - n*576;
    int t = kp>>6, ci = kp&63; int kh = t/3, kw = t - kh*3;
    float v = w[((n*64+ci)*3+kh)*3+kw];
    unsigned short hi,lo; split2(v,hi,lo);
    bhi[n*576+kp]=hi; blo[n*576+kp]=lo;
}

// ---- flat f32 -> bf16 convert
__global__ __launch_bounds__(256) void cvtbf16_k(const float* __restrict__ in,
                                                 unsigned short* __restrict__ out, int n){
    int i = blockIdx.x*256 + threadIdx.x;
    if (i < n) out[i] = f2bf(in[i]);
}

// ---- zero the 1-px border of padded f1 (386x386x64), hi+lo; run once
__global__ __launch_bounds__(256) void zpad_k(unsigned short* __restrict__ f1hi,
                                              unsigned short* __restrict__ f1lo){
    int idx = blockIdx.x*256 + threadIdx.x;
    if (idx >= 1540*8) return;
    int pi = idx>>3, c8 = (idx&7)*8;
    int p;
    if (pi < 386)       p = pi;                       // top row
    else if (pi < 772)  p = 385*386 + (pi-386);       // bottom row
    else if (pi < 1156) p = (pi-772+1)*386;           // left col rows 1..384
    else                p = (pi-1156+1)*386 + 385;    // right col rows 1..384
    float4 z = {0.f,0.f,0.f,0.f};
    *(float4*)(f1hi + (size_t)p*64 + c8) = z;
    *(float4*)(f1lo + (size_t)p*64 + c8) = z;
}

// ---- conv1 3->64 3x3 SAME + BN + GELU; padded (386x386) NHWC split-2 bf16 (one image)
// Block swizzle XCD-aligned with conv2's reader: pixels [18432*x,18432*(x+1)) on XCD x.
__global__ __launch_bounds__(256) void conv1_k(const float* __restrict__ x,
                                               const float* __restrict__ w,
                                               const float* __restrict__ bnp,
                                               unsigned short* __restrict__ f1hi,
                                               unsigned short* __restrict__ f1lo){
    __shared__ float ws[64*27];
    __shared__ float xr[32*28];
    __shared__ float s1[64], sh1[64];
    int tid = threadIdx.x;
    for (int i=tid;i<1728;i+=256) ws[i] = w[i];
    if (tid < 64){ s1[tid] = bnp[tid]; sh1[tid] = bnp[64+tid]; }
    int px = tid>>3, cg = tid&7;
    int bid = blockIdx.x;
    int swb = (bid&7)*576 + (bid>>3);      // 4608 blocks, XCD-aligned
    int p = swb*32 + px;                   // pixel
    int h = p/384, wq = p - h*384;
    for (int j=cg; j<27; j+=8){
        int ci = j/9, t9 = j - ci*9; int kh = t9/3, kw = t9 - kh*3;
        int y = h+kh-1, xx = wq+kw-1;
        float v = 0.f;
        if ((unsigned)y<384u && (unsigned)xx<384u)
            v = x[ci*147456 + y*384 + xx];
        xr[px*28+j] = v;
    }
    __syncthreads();
    float a[8];
    #pragma unroll
    for (int u=0;u<8;u++) a[u]=0.f;
    #pragma unroll
    for (int j=0;j<27;j++){
        float xv = xr[px*28+j];
        #pragma unroll
        for (int u=0;u<8;u++) a[u] += xv*ws[(cg*8+u)*27+j];
    }
    unsigned short hs[8], ls[8];
    #pragma unroll
    for (int u=0;u<8;u++){
        int co = cg*8+u;
        float v = gelu_f(a[u]*s1[co] + sh1[co]);
        split2(v, hs[u], ls[u]);
    }
    size_t off = ((size_t)(h+1)*386 + (wq+1))*64 + cg*8;
    *(float4*)(f1hi + off) = *(float4*)hs;
    *(float4*)(f1lo + off) = *(float4*)ls;
}

// ---- conv2 via split-2 bf16 MFMA (LDS-staged, 2 barriers/tap, 3 waves). One image.
// Fused epilogue: Ac16 bf16 (channel-major per cell) + {sum,sumsq} partials per
// (cell, row-in-cell, channel). No f32 feature map is materialized.
__global__ __launch_bounds__(192) void conv2_mfma_k(
        const unsigned short* __restrict__ f1hi, const unsigned short* __restrict__ f1lo,
        const unsigned short* __restrict__ bhi,  const unsigned short* __restrict__ blo,
        const float* __restrict__ bnsc, const float* __restrict__ bnsh,
        unsigned short* __restrict__ Ac, float* __restrict__ parts){
    __shared__ __align__(16) unsigned short Ah[192*68], Al[192*68];
    __shared__ __align__(16) unsigned short Bh[64*68],  Bl[64*68];
    const int tid = threadIdx.x;
    const int bid = blockIdx.x;
    const int swz = (bid&7)*96 + (bid>>3);     // 768 blocks, XCD-aligned with conv1
    const int bm = swz*192;
    const int y = bm/384, x0 = bm - y*384;     // x0 in {0,192}
    const int wv = tid>>6, lane = tid&63, lm = lane&15, q = lane>>4;

    f32x4 acc[4][4];
    #pragma unroll
    for (int i=0;i<4;i++)
        #pragma unroll
        for (int j=0;j<4;j++) acc[i][j] = (f32x4){0.f,0.f,0.f,0.f};

    for (int t9=0; t9<9; t9++){
        const int kh = t9/3, kw = t9 - kh*3;
        #pragma unroll
        for (int i=0;i<8;i++){
            int ch = tid + i*192;
            int pr = ch>>3, c8 = (ch&7)*8;
            size_t off = ((size_t)((y+kh)*386 + (x0+pr+kw)))*64 + c8;   // pad absorbs -1
            *(float4*)(Ah + pr*68 + c8) = *(const float4*)(f1hi + off);
            *(float4*)(Al + pr*68 + c8) = *(const float4*)(f1lo + off);
        }
        #pragma unroll
        for (int i=0;i<3;i++){
            int ch = tid + i*192;
            if (ch < 512){
                int n = ch>>3, c8 = (ch&7)*8;
                size_t off = (size_t)n*576 + t9*64 + c8;
                *(float4*)(Bh + n*68 + c8) = *(const float4*)(bhi + off);
                *(float4*)(Bl + n*68 + c8) = *(const float4*)(blo + off);
            }
        }
        __syncthreads();
        #pragma unroll
        for (int h=0; h<2; h++){
            bf16x8 ah[4], al[4], bh8[4], bl8[4];
            #pragma unroll
            for (int mi=0;mi<4;mi++){
                int row = wv*64 + mi*16 + lm;
                ah[mi] = *(const bf16x8*)(Ah + row*68 + h*32 + q*8);
                al[mi] = *(const bf16x8*)(Al + row*68 + h*32 + q*8);
            }
            #pragma unroll
            for (int nj=0;nj<4;nj++){
                int row = nj*16 + lm;
                bh8[nj] = *(const bf16x8*)(Bh + row*68 + h*32 + q*8);
                bl8[nj] = *(const bf16x8*)(Bl + row*68 + h*32 + q*8);
            }
            #pragma unroll
            for (int mi=0;mi<4;mi++)
                #pragma unroll
                for (int nj=0;nj<4;nj++){
                    acc[mi][nj] = __builtin_amdgcn_mfma_f32_16x16x32_bf16(ah[mi], bh8[nj], acc[mi][nj], 0,0,0);
                    acc[mi][nj] = __builtin_amdgcn_mfma_f32_16x16x32_bf16(al[mi], bh8[nj], acc[mi][nj], 0,0,0);
                    acc[mi][nj] = __builtin_amdgcn_mfma_f32_16x16x32_bf16(ah[mi], bl8[nj], acc[mi][nj], 0,0,0);
                }
        }
        __syncthreads();
    }

    // ---- fused epilogue: gelu -> Ac16 bf16 + per-cell-row {sum,sumsq} partials
    const int gy = y>>4, py = y&15;
    #pragma unroll
    for (int mi=0;mi<4;mi++){
        const int xb = x0 + wv*64 + mi*16;          // 16-aligned pixel-col base
        const int cell = gy*24 + (xb>>4);
        unsigned short* acb = Ac + (size_t)cell*16384;
        float* pp = parts + (size_t)(cell*16 + py)*128;   // 64 ch * 2 floats
        #pragma unroll
        for (int nj=0;nj<4;nj++){
            const int n = nj*16 + lm;
            const float sc = bnsc[n], sh = bnsh[n];
            float g0 = gelu_f(acc[mi][nj][0]*sc + sh);
            float g1 = gelu_f(acc[mi][nj][1]*sc + sh);
            float g2 = gelu_f(acc[mi][nj][2]*sc + sh);
            float g3 = gelu_f(acc[mi][nj][3]*sc + sh);
            // Ac16: k = n*256 + py*16 + (q*4 + r), 8B store
            unsigned int u0 = (unsigned)f2bf(g0) | ((unsigned)f2bf(g1)<<16);
            unsigned int u1 = (unsigned)f2bf(g2) | ((unsigned)f2bf(g3)<<16);
            uint2 uu; uu.x = u0; uu.y = u1;
            *(uint2*)(acb + (size_t)n*256 + py*16 + q*4) = uu;
            // partial sum/sumsq over this 16-px cell-row slice
            float s  = ((g0+g1)+g2)+g3;
            float ss = ((g0*g0+g1*g1)+g2*g2)+g3*g3;
            s  += __shfl_xor(s,16);  s  += __shfl_xor(s,32);
            ss += __shfl_xor(ss,16); ss += __shfl_xor(ss,32);
            if (q==0){
                float2 v; v.x = s; v.y = ss;
                *(float2*)(pp + n*2) = v;
            }
        }
    }
}

// ---- per-cell score from partials: var = E[x^2]-E[x]^2 per ch, mean over ch
__global__ __launch_bounds__(64) void score_k(const float* __restrict__ parts,
                                              float* __restrict__ scores){
    const int cell = blockIdx.x;       // 0..575
    const int n = threadIdx.x;         // channel
    float s = 0.f, ss = 0.f;
    #pragma unroll
    for (int py=0;py<16;py++){
        float2 v = *(const float2*)(parts + (size_t)(cell*16+py)*128 + n*2);
        s += v.x; ss += v.y;
    }
    float mean = s*(1.f/256.f);
    float var  = ss*(1.f/256.f) - mean*mean;
    var += __shfl_down(var,32); var += __shfl_down(var,16);
    var += __shfl_down(var,8);  var += __shfl_down(var,4);
    var += __shfl_down(var,2);  var += __shfl_down(var,1);
    if (n==0) scores[cell] = var*(1.f/64.f);
}

// ---- generic bf16 MFMA GEMM: tile M=64 x N=128, 256 thr (4 waves), K-split z
// MODE 0: coarse  A=Ac16 rows [576][16384]
// MODE 1: detail  A=Ac16 gathered: row=(topk[sel],dy,dx), k=c*64+qy*8+qx
// MODE 2: merge   A=dp16 rows [1024][3072]
template<int MODE, int KL, int MT>
__global__ __launch_bounds__(256) void gemm16_k(const unsigned short* __restrict__ A,
                                                const unsigned short* __restrict__ W,
                                                const int* __restrict__ topk,
                                                float* __restrict__ part){
    constexpr int KT = (MODE==0)?16384:(MODE==1)?4096:3072;   // W row length
    __shared__ __align__(16) unsigned short As[64*40];
    __shared__ __align__(16) unsigned short Bs[128*40];
    const int tid = threadIdx.x;
    const int nt = blockIdx.x, mt = blockIdx.y, z = blockIdx.z;
    const int m0 = mt*64, n0 = nt*128;
    const int wv = tid>>6, lane = tid&63;
    const int lm = lane&15, q = lane>>4;
    const int ar = tid>>2, ak = (tid&3)*8;

    size_t abase;
    if (MODE==1){
        int t = m0 + ar; int sel = t>>2, dd = t&3;
        int cell = topk[sel];
        abase = (size_t)cell*16384 + (dd>>1)*128 + (dd&1)*8;
    } else if (MODE==0){
        abase = (size_t)(m0+ar)*16384;
    } else {
        abase = (size_t)(m0+ar)*3072;
    }

    f32x4 acc[4][2];
    #pragma unroll
    for (int i=0;i<4;i++)
        #pragma unroll
        for (int j=0;j<2;j++)
            acc[i][j] = (f32x4){0.f,0.f,0.f,0.f};

    const int kb0 = z*KL;
    for (int kb = kb0; kb < kb0+KL; kb += 32){
        {
            int k0 = kb + ak;
            size_t src = (MODE==1) ? (abase + (k0>>6)*256 + ((k0>>3)&7)*16)
                                   : (abase + k0);
            const float4 v = *(const float4*)(A + src);
            *(float4*)(&As[ar*40 + ak]) = v;
        }
        #pragma unroll
        for (int i=0;i<2;i++){
            const float4 v = *(const float4*)(W + (size_t)(n0+ar+i*64)*KT + kb + ak);
            *(float4*)(&Bs[(ar+i*64)*40 + ak]) = v;
        }
        __syncthreads();
        bf16x8 af[4], bb[2];
        #pragma unroll
        for (int mi=0;mi<4;mi++) af[mi] = *(const bf16x8*)(&As[(mi*16+lm)*40 + q*8]);
        #pragma unroll
        for (int nj=0;nj<2;nj++) bb[nj] = *(const bf16x8*)(&Bs[(wv*32+nj*16+lm)*40 + q*8]);
        #pragma unroll
        for (int mi=0;mi<4;mi++)
            #pragma unroll
            for (int nj=0;nj<2;nj++)
                acc[mi][nj] = __builtin_amdgcn_mfma_f32_16x16x32_bf16(af[mi], bb[nj], acc[mi][nj], 0,0,0);
        __syncthreads();
    }

    float* pz = part + (size_t)z*MT*768;
    #pragma unroll
    for (int mi=0;mi<4;mi++)
        #pragma unroll
        for (int nj=0;nj<2;nj++)
            #pragma unroll
            for (int r=0;r<4;r++){
                int m = m0 + mi*16 + q*4 + r;
                int n = n0 + wv*32 + nj*16 + lm;
                pz[m*768 + n] = acc[mi][nj][r];
            }
}

// ---- sum K-split partials + bias -> f32
__global__ __launch_bounds__(256) void reduce_k(const float* __restrict__ partials,
                                                const float* __restrict__ bias,
                                                float* __restrict__ outp,
                                                int MTOT, int NSPLIT){
    int idx = blockIdx.x*256 + threadIdx.x;
    int col = idx % 768;
    float s = bias[col];
    for (int i=0;i<NSPLIT;i++) s += partials[(size_t)i*MTOT*768 + idx];
    outp[idx] = s;
}

// ---- sum K-split partials + bias -> bf16
__global__ __launch_bounds__(256) void reduce16_k(const float* __restrict__ partials,
                                                  const float* __restrict__ bias,
                                                  unsigned short* __restrict__ outp,
                                                  int MTOT, int NSPLIT){
    int idx = blockIdx.x*256 + threadIdx.x;
    int col = idx % 768;
    float s = bias[col];
    for (int i=0;i<NSPLIT;i++) s += partials[(size_t)i*MTOT*768 + idx];
    outp[idx] = f2bf(s);
}

// ---- top-64 of 576 via rank counting; jax tie-break (lower idx first), one shot
__global__ __launch_bounds__(576) void topk_k(const float* __restrict__ scores,
                                              int* __restrict__ topk,
                                              float* __restrict__ outf){
    __shared__ float s[576];
    int t = threadIdx.x;
    s[t] = scores[t];
    __syncthreads();
    float v = s[t];
    int cnt = 0;
    for (int j=0;j<576;j++){
        float u = s[j];
        cnt += (u > v) || (u == v && j < t);
    }
    if (cnt < 64){ topk[cnt] = t; outf[cnt] = (float)t; }
}

extern "C" void kernel_launch(void* const* d_in, const int* in_sizes, int n_in,
                              void* d_out, int out_size, void* d_ws, size_t ws_size,
                              hipStream_t stream){
    const float* x       = (const float*)d_in[0];
    const float* conv1_w = (const float*)d_in[1];
    const float* bn1_g   = (const float*)d_in[2];
    const float* bn1_b   = (const float*)d_in[3];
    const float* bn1_m   = (const float*)d_in[4];
    const float* bn1_v   = (const float*)d_in[5];
    const float* conv2_w = (const float*)d_in[6];
    const float* bn2_g   = (const float*)d_in[7];
    const float* bn2_b   = (const float*)d_in[8];
    const float* bn2_m   = (const float*)d_in[9];
    const float* bn2_v   = (const float*)d_in[10];
    const float* coarse_w= (const float*)d_in[11];
    const float* coarse_b= (const float*)d_in[12];
    const float* detail_w= (const float*)d_in[13];
    const float* detail_b= (const float*)d_in[14];
    const float* merge_w = (const float*)d_in[15];
    const float* merge_b = (const float*)d_in[16];
    float* out = (float*)d_out;

    // ---- workspace layout (float units); ~152 MB ----
    float* wsp  = (float*)d_ws;
    unsigned short* f1hi = (unsigned short*)wsp;         // 9,535,744 bf16 (386*386*64)
    unsigned short* f1lo = f1hi + 9535744;               // 9,535,744 bf16
    float* parts = wsp + 9535744;                        // 1,179,648 f32 (slot 9.4M)
    float* bnp  = parts + 9437184;                       // 256
    float* scores = bnp + 256;                           // 9,216
    int*   topk = (int*)(scores + 9216);                 // 1,024
    unsigned short* B2hi = (unsigned short*)(topk + 1024);   // 36,864 bf16
    unsigned short* B2lo = B2hi + 36864;                     // 36,864 bf16
    unsigned short* Wc16 = B2lo + 36864;                     // 12,582,912 bf16
    unsigned short* Wd16 = Wc16 + 12582912;                  // 3,145,728 bf16
    unsigned short* Wm16 = Wd16 + 3145728;                   // 2,359,296 bf16
    unsigned short* Ac16 = Wm16 + 2359296;                   // 9,437,184 bf16
    unsigned short* dp16 = Ac16 + 9437184;                   // 3,145,728 bf16
    float* part = (float*)(dp16 + 3145728);                  // 3,538,944 f32

    if (ws_size < (size_t)171000000) return;   // graceful fail if ws too small

    const int DETAIL_OFF = 16*576*768;            // 7077888
    const int IDX_OFF    = DETAIL_OFF + 16*64*768;// 7864320

    bnprep_k<<<1,64,0,stream>>>(bn1_g,bn1_b,bn1_m,bn1_v, bn2_g,bn2_b,bn2_m,bn2_v, bnp);
    w2prep_k<<<144,256,0,stream>>>(conv2_w, B2hi, B2lo);
    cvtbf16_k<<<49152,256,0,stream>>>(coarse_w, Wc16, 12582912);
    cvtbf16_k<<<12288,256,0,stream>>>(detail_w, Wd16, 3145728);
    cvtbf16_k<<<9216,256,0,stream>>>(merge_w,  Wm16, 2359296);
    zpad_k<<<49,256,0,stream>>>(f1hi, f1lo);     // once: borders stay zero

    for (int b = 0; b < 16; b++){
        conv1_k<<<4608,256,0,stream>>>(x + (size_t)b*442368, conv1_w, bnp, f1hi, f1lo);
        conv2_mfma_k<<<768,192,0,stream>>>(f1hi, f1lo, B2hi, B2lo, bnp+128, bnp+192,
                                           Ac16, parts);
        score_k<<<576,64,0,stream>>>(parts, scores + b*576);
        topk_k<<<1,576,0,stream>>>(scores + b*576, topk + b*64, out + IDX_OFF + b*64);
        // coarse tokens
        gemm16_k<0,2048,576><<<dim3(6,9,8),256,0,stream>>>(Ac16, Wc16, nullptr, part);
        reduce_k<<<1728,256,0,stream>>>(part, coarse_b, out + (size_t)b*442368, 576, 8);
        // detail tokens (selected) — A gathered from Ac16
        gemm16_k<1,1024,256><<<dim3(6,4,4),256,0,stream>>>(Ac16, Wd16, topk + b*64, part);
        reduce16_k<<<768,256,0,stream>>>(part, detail_b, dp16 + (size_t)b*196608, 256, 4);
    }

    // merge over all batches: M=1024, K=3072
    gemm16_k<2,768,1024><<<dim3(6,16,4),256,0,stream>>>(dp16, Wm16, nullptr, part);
    reduce_k<<<3072,256,0,stream>>>(part, merge_b, out + DETAIL_OFF, 1024, 4);
}

// Round 5
// 3130.977 us; speedup vs baseline: 1.4284x; 1.1405x over previous
//
#include <hip/hip_runtime.h>
#include <math.h>

// Shapes (fixed): B=16, Cin=3, C=64, H=W=384, E=768, P=16, G=24, K_sel=64
// conv2 v5: 192-thr LDS-staged MFMA, staging via global_load_lds (width 16),
//           linear LDS rows + XOR slot swizzle on BOTH source and read (rule #21).
//           Fused epilogue: Ac16 bf16 + {sum,sumsq} partials. fb eliminated.
// conv1 v2: coalesced halo staging ([ci][kh][34]), broadcast compute.
// coarse: M=576,N=768,K=16384  detail(sel): M=256,N=768,K=4096  merge: M=1024,N=768,K=3072

__device__ __forceinline__ float gelu_f(float v){
    return 0.5f*v*(1.0f + erff(v*0.70710678118654752440f));
}
__device__ __forceinline__ unsigned short f2bf(float v){
    unsigned u = __float_as_uint(v);
    return (unsigned short)((u + 0x7FFFu + ((u>>16)&1u)) >> 16);   // RNE
}
__device__ __forceinline__ float bf2f(unsigned short h){
    return __uint_as_float(((unsigned)h)<<16);
}
__device__ __forceinline__ void split2(float v, unsigned short& hi, unsigned short& lo){
    hi = f2bf(v);
    lo = f2bf(v - bf2f(hi));
}

typedef short bf16x8 __attribute__((ext_vector_type(8)));
typedef float f32x4  __attribute__((ext_vector_type(4)));

// ---- BN scale/shift: out[0..63]=s1, [64..127]=sh1, [128..191]=s2, [192..255]=sh2
__global__ void bnprep_k(const float* g1,const float* b1,const float* m1,const float* v1,
                         const float* g2,const float* b2,const float* m2,const float* v2,
                         float* outp){
    int t = threadIdx.x;
    if (t < 64){
        float s = g1[t]/sqrtf(v1[t]+1e-5f);
        outp[t] = s; outp[64+t] = b1[t]-m1[t]*s;
        float s2 = g2[t]/sqrtf(v2[t]+1e-5f);
        outp[128+t] = s2; outp[192+t] = b2[t]-m2[t]*s2;
    }
}

// ---- conv2 weights -> split-2 bf16, n-major [64][576], k' = (kh*3+kw)*64 + ci
__global__ void w2prep_k(const float* __restrict__ w,
                         unsigned short* __restrict__ bhi, unsigned short* __restrict__ blo){
    int idx = blockIdx.x*256 + threadIdx.x;
    if (idx >= 36864) return;
    int n = idx/576, kp = idx - n*576;
    int t = kp>>6, ci = kp&63; int kh = t/3, kw = t - kh*3;
    float v = w[((n*64+ci)*3+kh)*3+kw];
    unsigned short hi,lo; split2(v,hi,lo);
    bhi[n*576+kp]=hi; blo[n*576+kp]=lo;
}

// ---- flat f32 -> bf16 convert
__global__ __launch_bounds__(256) void cvtbf16_k(const float* __restrict__ in,
                                                 unsigned short* __restrict__ out, int n){
    int i = blockIdx.x*256 + threadIdx.x;
    if (i < n) out[i] = f2bf(in[i]);
}

// ---- zero the 1-px border of padded f1 (386x386x64), hi+lo; run once
__global__ __launch_bounds__(256) void zpad_k(unsigned short* __restrict__ f1hi,
                                              unsigned short* __restrict__ f1lo){
    int idx = blockIdx.x*256 + threadIdx.x;
    if (idx >= 1540*8) return;
    int pi = idx>>3, c8 = (idx&7)*8;
    int p;
    if (pi < 386)       p = pi;                       // top row
    else if (pi < 772)  p = 385*386 + (pi-386);       // bottom row
    else if (pi < 1156) p = (pi-772+1)*386;           // left col rows 1..384
    else                p = (pi-1156+1)*386 + 385;    // right col rows 1..384
    float4 z = {0.f,0.f,0.f,0.f};
    *(float4*)(f1hi + (size_t)p*64 + c8) = z;
    *(float4*)(f1lo + (size_t)p*64 + c8) = z;
}

// ---- conv1 3->64 3x3 SAME + BN + GELU; padded (386x386) NHWC split-2 bf16 (one image)
// Coalesced halo staging: 306 floats [ci][kh][34]; compute reads broadcast from LDS.
// Block swizzle XCD-aligned with conv2's reader.
__global__ __launch_bounds__(256) void conv1_k(const float* __restrict__ x,
                                               const float* __restrict__ w,
                                               const float* __restrict__ bnp,
                                               unsigned short* __restrict__ f1hi,
                                               unsigned short* __restrict__ f1lo){
    __shared__ float ws[64*27];
    __shared__ float xr[9*34];
    __shared__ float s1[64], sh1[64];
    int tid = threadIdx.x;
    for (int i=tid;i<1728;i+=256) ws[i] = w[i];
    if (tid < 64){ s1[tid] = bnp[tid]; sh1[tid] = bnp[64+tid]; }
    int bid = blockIdx.x;
    int swb = (bid&7)*576 + (bid>>3);      // 4608 blocks, XCD-aligned
    int p0 = swb*32;
    int h0 = p0/384, x0 = p0 - h0*384;     // 32 | 384 -> row-uniform block
    for (int t=tid; t<306; t+=256){
        int ci = t/102, rem = t - ci*102;
        int kh = rem/34, col = rem - kh*34;
        int y = h0+kh-1, xx = x0+col-1;
        float v = 0.f;
        if ((unsigned)y<384u && (unsigned)xx<384u)
            v = x[ci*147456 + y*384 + xx];
        xr[(ci*3+kh)*34 + col] = v;
    }
    __syncthreads();
    int px = tid>>3, cg = tid&7;
    float a[8];
    #pragma unroll
    for (int u=0;u<8;u++) a[u]=0.f;
    #pragma unroll
    for (int ci=0;ci<3;ci++)
        #pragma unroll
        for (int kh=0;kh<3;kh++)
            #pragma unroll
            for (int kw=0;kw<3;kw++){
                const int j = (ci*3+kh)*3+kw;            // same j order as before
                float xv = xr[(ci*3+kh)*34 + px + kw];
                #pragma unroll
                for (int u=0;u<8;u++) a[u] += xv*ws[(cg*8+u)*27+j];
            }
    unsigned short hs[8], ls[8];
    #pragma unroll
    for (int u=0;u<8;u++){
        int co = cg*8+u;
        float v = gelu_f(a[u]*s1[co] + sh1[co]);
        split2(v, hs[u], ls[u]);
    }
    size_t off = ((size_t)(h0+1)*386 + (x0+px+1))*64 + cg*8;
    *(float4*)(f1hi + off) = *(float4*)hs;
    *(float4*)(f1lo + off) = *(float4*)ls;
}

// ---- conv2 via split-2 bf16 MFMA (LDS-staged via global_load_lds, 2 barriers/tap,
// 3 waves). Linear 64-short LDS rows; slot XOR swizzle applied to BOTH the global
// source address and the ds_read address (involution, rule #21). One image.
// Fused epilogue: Ac16 bf16 + per-(cell,row,ch) {sum,sumsq} partials.
__global__ __launch_bounds__(192) void conv2_mfma_k(
        const unsigned short* __restrict__ f1hi, const unsigned short* __restrict__ f1lo,
        const unsigned short* __restrict__ bhi,  const unsigned short* __restrict__ blo,
        const float* __restrict__ bnsc, const float* __restrict__ bnsh,
        unsigned short* __restrict__ Ac, float* __restrict__ parts){
    __shared__ __align__(16) unsigned short AhL[192*64], AlL[192*64];
    __shared__ __align__(16) unsigned short BhL[64*64],  BlL[64*64];
    const int tid = threadIdx.x;
    const int bid = blockIdx.x;
    const int swz = (bid&7)*96 + (bid>>3);     // 768 blocks, XCD-aligned with conv1
    const int bm = swz*192;
    const int y = bm/384, x0 = bm - y*384;     // x0 in {0,192}
    const int wv = tid>>6, lane = tid&63, lm = lane&15, q = lane>>4;

    // staging sources (per-thread constants; tap adds an offset)
    int aSrc[8];
    #pragma unroll
    for (int i=0;i<8;i++){
        int ch = tid + i*192;
        int pr = ch>>3, p8 = ch&7;
        aSrc[i] = (y*386 + x0 + pr)*64 + ((p8 ^ (pr&7))<<3);   // pad absorbs -1
    }
    int bSrc[3];
    #pragma unroll
    for (int i=0;i<3;i++){
        int ch = tid + i*192;
        int n = ch>>3, p8 = ch&7;
        bSrc[i] = n*576 + ((p8 ^ (n&7))<<3);
    }
    // ds_read byte addrs (swizzled), per-thread constants
    int aRd[4][2], bRd[4][2];
    #pragma unroll
    for (int mi=0;mi<4;mi++){
        int r = wv*64 + mi*16 + lm;
        #pragma unroll
        for (int h=0;h<2;h++)
            aRd[mi][h] = r*128 + (((h*4+q) ^ (r&7))<<4);
    }
    #pragma unroll
    for (int nj=0;nj<4;nj++){
        int r = nj*16 + lm;
        #pragma unroll
        for (int h=0;h<2;h++)
            bRd[nj][h] = r*128 + (((h*4+q) ^ (r&7))<<4);
    }

    f32x4 acc[4][4];
    #pragma unroll
    for (int i=0;i<4;i++)
        #pragma unroll
        for (int j=0;j<4;j++) acc[i][j] = (f32x4){0.f,0.f,0.f,0.f};

    for (int t9=0; t9<9; t9++){
        const int kh = t9/3, kw = t9 - kh*3;
        const int aoff = (kh*386 + kw)*64;
        const int boff = t9*64;
        #pragma unroll
        for (int i=0;i<8;i++){
            __builtin_amdgcn_global_load_lds(f1hi + aSrc[i] + aoff, &AhL[(tid+i*192)*8], 16, 0, 0);
            __builtin_amdgcn_global_load_lds(f1lo + aSrc[i] + aoff, &AlL[(tid+i*192)*8], 16, 0, 0);
        }
        #pragma unroll
        for (int i=0;i<3;i++){
            int ch = tid + i*192;
            if (ch < 512){   // wave-uniform: i=2 skips wave 2 entirely
                __builtin_amdgcn_global_load_lds(bhi + bSrc[i] + boff, &BhL[ch*8], 16, 0, 0);
                __builtin_amdgcn_global_load_lds(blo + bSrc[i] + boff, &BlL[ch*8], 16, 0, 0);
            }
        }
        __syncthreads();
        #pragma unroll
        for (int h=0; h<2; h++){
            bf16x8 ah[4], al[4], bh8[4], bl8[4];
            #pragma unroll
            for (int mi=0;mi<4;mi++){
                ah[mi] = *(const bf16x8*)((const char*)AhL + aRd[mi][h]);
                al[mi] = *(const bf16x8*)((const char*)AlL + aRd[mi][h]);
            }
            #pragma unroll
            for (int nj=0;nj<4;nj++){
                bh8[nj] = *(const bf16x8*)((const char*)BhL + bRd[nj][h]);
                bl8[nj] = *(const bf16x8*)((const char*)BlL + bRd[nj][h]);
            }
            #pragma unroll
            for (int mi=0;mi<4;mi++)
                #pragma unroll
                for (int nj=0;nj<4;nj++){
                    acc[mi][nj] = __builtin_amdgcn_mfma_f32_16x16x32_bf16(ah[mi], bh8[nj], acc[mi][nj], 0,0,0);
                    acc[mi][nj] = __builtin_amdgcn_mfma_f32_16x16x32_bf16(al[mi], bh8[nj], acc[mi][nj], 0,0,0);
                    acc[mi][nj] = __builtin_amdgcn_mfma_f32_16x16x32_bf16(ah[mi], bl8[nj], acc[mi][nj], 0,0,0);
                }
        }
        __syncthreads();
    }

    // ---- fused epilogue: gelu -> Ac16 bf16 + per-cell-row {sum,sumsq} partials
    const int gy = y>>4, py = y&15;
    #pragma unroll
    for (int mi=0;mi<4;mi++){
        const int xb = x0 + wv*64 + mi*16;          // 16-aligned pixel-col base
        const int cell = gy*24 + (xb>>4);
        unsigned short* acb = Ac + (size_t)cell*16384;
        float* pp = parts + (size_t)(cell*16 + py)*128;   // 64 ch * 2 floats
        #pragma unroll
        for (int nj=0;nj<4;nj++){
            const int n = nj*16 + lm;
            const float sc = bnsc[n], sh = bnsh[n];
            float g0 = gelu_f(acc[mi][nj][0]*sc + sh);
            float g1 = gelu_f(acc[mi][nj][1]*sc + sh);
            float g2 = gelu_f(acc[mi][nj][2]*sc + sh);
            float g3 = gelu_f(acc[mi][nj][3]*sc + sh);
            // Ac16: k = n*256 + py*16 + (q*4 + r), 8B store
            unsigned int u0 = (unsigned)f2bf(g0) | ((unsigned)f2bf(g1)<<16);
            unsigned int u1 = (unsigned)f2bf(g2) | ((unsigned)f2bf(g3)<<16);
            uint2 uu; uu.x = u0; uu.y = u1;
            *(uint2*)(acb + (size_t)n*256 + py*16 + q*4) = uu;
            // partial sum/sumsq over this 16-px cell-row slice
            float s  = ((g0+g1)+g2)+g3;
            float ss = ((g0*g0+g1*g1)+g2*g2)+g3*g3;
            s  += __shfl_xor(s,16);  s  += __shfl_xor(s,32);
            ss += __shfl_xor(ss,16); ss += __shfl_xor(ss,32);
            if (q==0){
                float2 v; v.x = s; v.y = ss;
                *(float2*)(pp + n*2) = v;
            }
        }
    }
}

// ---- per-cell score from partials: var = E[x^2]-E[x]^2 per ch, mean over ch
__global__ __launch_bounds__(64) void score_k(const float* __restrict__ parts,
                                              float* __restrict__ scores){
    const int cell = blockIdx.x;       // 0..575
    const int n = threadIdx.x;         // channel
    float s = 0.f, ss = 0.f;
    #pragma unroll
    for (int py=0;py<16;py++){
        float2 v = *(const float2*)(parts + (size_t)(cell*16+py)*128 + n*2);
        s += v.x; ss += v.y;
    }
    float mean = s*(1.f/256.f);
    float var  = ss*(1.f/256.f) - mean*mean;
    var += __shfl_down(var,32); var += __shfl_down(var,16);
    var += __shfl_down(var,8);  var += __shfl_down(var,4);
    var += __shfl_down(var,2);  var += __shfl_down(var,1);
    if (n==0) scores[cell] = var*(1.f/64.f);
}

// ---- generic bf16 MFMA GEMM: tile M=64 x N=128, 256 thr (4 waves), K-split z
// MODE 0: coarse  A=Ac16 rows [576][16384]
// MODE 1: detail  A=Ac16 gathered: row=(topk[sel],dy,dx), k=c*64+qy*8+qx
// MODE 2: merge   A=dp16 rows [1024][3072]
template<int MODE, int KL, int MT>
__global__ __launch_bounds__(256) void gemm16_k(const unsigned short* __restrict__ A,
                                                const unsigned short* __restrict__ W,
                                                const int* __restrict__ topk,
                                                float* __restrict__ part){
    constexpr int KT = (MODE==0)?16384:(MODE==1)?4096:3072;   // W row length
    __shared__ __align__(16) unsigned short As[64*40];
    __shared__ __align__(16) unsigned short Bs[128*40];
    const int tid = threadIdx.x;
    const int nt = blockIdx.x, mt = blockIdx.y, z = blockIdx.z;
    const int m0 = mt*64, n0 = nt*128;
    const int wv = tid>>6, lane = tid&63;
    const int lm = lane&15, q = lane>>4;
    const int ar = tid>>2, ak = (tid&3)*8;

    size_t abase;
    if (MODE==1){
        int t = m0 + ar; int sel = t>>2, dd = t&3;
        int cell = topk[sel];
        abase = (size_t)cell*16384 + (dd>>1)*128 + (dd&1)*8;
    } else if (MODE==0){
        abase = (size_t)(m0+ar)*16384;
    } else {
        abase = (size_t)(m0+ar)*3072;
    }

    f32x4 acc[4][2];
    #pragma unroll
    for (int i=0;i<4;i++)
        #pragma unroll
        for (int j=0;j<2;j++)
            acc[i][j] = (f32x4){0.f,0.f,0.f,0.f};

    const int kb0 = z*KL;
    for (int kb = kb0; kb < kb0+KL; kb += 32){
        {
            int k0 = kb + ak;
            size_t src = (MODE==1) ? (abase + (k0>>6)*256 + ((k0>>3)&7)*16)
                                   : (abase + k0);
            const float4 v = *(const float4*)(A + src);
            *(float4*)(&As[ar*40 + ak]) = v;
        }
        #pragma unroll
        for (int i=0;i<2;i++){
            const float4 v = *(const float4*)(W + (size_t)(n0+ar+i*64)*KT + kb + ak);
            *(float4*)(&Bs[(ar+i*64)*40 + ak]) = v;
        }
        __syncthreads();
        bf16x8 af[4], bb[2];
        #pragma unroll
        for (int mi=0;mi<4;mi++) af[mi] = *(const bf16x8*)(&As[(mi*16+lm)*40 + q*8]);
        #pragma unroll
        for (int nj=0;nj<2;nj++) bb[nj] = *(const bf16x8*)(&Bs[(wv*32+nj*16+lm)*40 + q*8]);
        #pragma unroll
        for (int mi=0;mi<4;mi++)
            #pragma unroll
            for (int nj=0;nj<2;nj++)
                acc[mi][nj] = __builtin_amdgcn_mfma_f32_16x16x32_bf16(af[mi], bb[nj], acc[mi][nj], 0,0,0);
        __syncthreads();
    }

    float* pz = part + (size_t)z*MT*768;
    #pragma unroll
    for (int mi=0;mi<4;mi++)
        #pragma unroll
        for (int nj=0;nj<2;nj++)
            #pragma unroll
            for (int r=0;r<4;r++){
                int m = m0 + mi*16 + q*4 + r;
                int n = n0 + wv*32 + nj*16 + lm;
                pz[m*768 + n] = acc[mi][nj][r];
            }
}

// ---- sum K-split partials + bias -> f32
__global__ __launch_bounds__(256) void reduce_k(const float* __restrict__ partials,
                                                const float* __restrict__ bias,
                                                float* __restrict__ outp,
                                                int MTOT, int NSPLIT){
    int idx = blockIdx.x*256 + threadIdx.x;
    int col = idx % 768;
    float s = bias[col];
    for (int i=0;i<NSPLIT;i++) s += partials[(size_t)i*MTOT*768 + idx];
    outp[idx] = s;
}

// ---- sum K-split partials + bias -> bf16
__global__ __launch_bounds__(256) void reduce16_k(const float* __restrict__ partials,
                                                  const float* __restrict__ bias,
                                                  unsigned short* __restrict__ outp,
                                                  int MTOT, int NSPLIT){
    int idx = blockIdx.x*256 + threadIdx.x;
    int col = idx % 768;
    float s = bias[col];
    for (int i=0;i<NSPLIT;i++) s += partials[(size_t)i*MTOT*768 + idx];
    outp[idx] = f2bf(s);
}

// ---- top-64 of 576 via rank counting; jax tie-break (lower idx first), one shot
__global__ __launch_bounds__(576) void topk_k(const float* __restrict__ scores,
                                              int* __restrict__ topk,
                                              float* __restrict__ outf){
    __shared__ float s[576];
    int t = threadIdx.x;
    s[t] = scores[t];
    __syncthreads();
    float v = s[t];
    int cnt = 0;
    for (int j=0;j<576;j++){
        float u = s[j];
        cnt += (u > v) || (u == v && j < t);
    }
    if (cnt < 64){ topk[cnt] = t; outf[cnt] = (float)t; }
}

extern "C" void kernel_launch(void* const* d_in, const int* in_sizes, int n_in,
                              void* d_out, int out_size, void* d_ws, size_t ws_size,
                              hipStream_t stream){
    const float* x       = (const float*)d_in[0];
    const float* conv1_w = (const float*)d_in[1];
    const float* bn1_g   = (const float*)d_in[2];
    const float* bn1_b   = (const float*)d_in[3];
    const float* bn1_m   = (const float*)d_in[4];
    const float* bn1_v   = (const float*)d_in[5];
    const float* conv2_w = (const float*)d_in[6];
    const float* bn2_g   = (const float*)d_in[7];
    const float* bn2_b   = (const float*)d_in[8];
    const float* bn2_m   = (const float*)d_in[9];
    const float* bn2_v   = (const float*)d_in[10];
    const float* coarse_w= (const float*)d_in[11];
    const float* coarse_b= (const float*)d_in[12];
    const float* detail_w= (const float*)d_in[13];
    const float* detail_b= (const float*)d_in[14];
    const float* merge_w = (const float*)d_in[15];
    const float* merge_b = (const float*)d_in[16];
    float* out = (float*)d_out;

    // ---- workspace layout (float units); ~152 MB ----
    float* wsp  = (float*)d_ws;
    unsigned short* f1hi = (unsigned short*)wsp;         // 9,535,744 bf16 (386*386*64)
    unsigned short* f1lo = f1hi + 9535744;               // 9,535,744 bf16
    float* parts = wsp + 9535744;                        // 1,179,648 f32 (slot 9.4M)
    float* bnp  = parts + 9437184;                       // 256
    float* scores = bnp + 256;                           // 9,216
    int*   topk = (int*)(scores + 9216);                 // 1,024
    unsigned short* B2hi = (unsigned short*)(topk + 1024);   // 36,864 bf16
    unsigned short* B2lo = B2hi + 36864;                     // 36,864 bf16
    unsigned short* Wc16 = B2lo + 36864;                     // 12,582,912 bf16
    unsigned short* Wd16 = Wc16 + 12582912;                  // 3,145,728 bf16
    unsigned short* Wm16 = Wd16 + 3145728;                   // 2,359,296 bf16
    unsigned short* Ac16 = Wm16 + 2359296;                   // 9,437,184 bf16
    unsigned short* dp16 = Ac16 + 9437184;                   // 3,145,728 bf16
    float* part = (float*)(dp16 + 3145728);                  // 3,538,944 f32

    if (ws_size < (size_t)171000000) return;   // graceful fail if ws too small

    const int DETAIL_OFF = 16*576*768;            // 7077888
    const int IDX_OFF    = DETAIL_OFF + 16*64*768;// 7864320

    bnprep_k<<<1,64,0,stream>>>(bn1_g,bn1_b,bn1_m,bn1_v, bn2_g,bn2_b,bn2_m,bn2_v, bnp);
    w2prep_k<<<144,256,0,stream>>>(conv2_w, B2hi, B2lo);
    cvtbf16_k<<<49152,256,0,stream>>>(coarse_w, Wc16, 12582912);
    cvtbf16_k<<<12288,256,0,stream>>>(detail_w, Wd16, 3145728);
    cvtbf16_k<<<9216,256,0,stream>>>(merge_w,  Wm16, 2359296);
    zpad_k<<<49,256,0,stream>>>(f1hi, f1lo);     // once: borders stay zero

    for (int b = 0; b < 16; b++){
        conv1_k<<<4608,256,0,stream>>>(x + (size_t)b*442368, conv1_w, bnp, f1hi, f1lo);
        conv2_mfma_k<<<768,192,0,stream>>>(f1hi, f1lo, B2hi, B2lo, bnp+128, bnp+192,
                                           Ac16, parts);
        score_k<<<576,64,0,stream>>>(parts, scores + b*576);
        topk_k<<<1,576,0,stream>>>(scores + b*576, topk + b*64, out + IDX_OFF + b*64);
        // coarse tokens
        gemm16_k<0,2048,576><<<dim3(6,9,8),256,0,stream>>>(Ac16, Wc16, nullptr, part);
        reduce_k<<<1728,256,0,stream>>>(part, coarse_b, out + (size_t)b*442368, 576, 8);
        // detail tokens (selected) — A gathered from Ac16
        gemm16_k<1,1024,256><<<dim3(6,4,4),256,0,stream>>>(Ac16, Wd16, topk + b*64, part);
        reduce16_k<<<768,256,0,stream>>>(part, detail_b, dp16 + (size_t)b*196608, 256, 4);
    }

    // merge over all batches: M=1024, K=3072
    gemm16_k<2,768,1024><<<dim3(6,16,4),256,0,stream>>>(dp16, Wm16, nullptr, part);
    reduce_k<<<3072,256,0,stream>>>(part, merge_b, out + DETAIL_OFF, 1024, 4);
}

// Round 6
// 2849.650 us; speedup vs baseline: 1.5694x; 1.0987x over previous
//
#include <hip/hip_runtime.h>
#include <math.h>

// Shapes (fixed): B=16, Cin=3, C=64, H=W=384, E=768, P=16, G=24, K_sel=64
// conv2 v5: 192-thr LDS-staged MFMA via global_load_lds(16), both-sides XOR swizzle.
//           Fused epilogue: Ac16 bf16 + {sum,sumsq} partials. fb eliminated.
// gemm16 v2: same recipe — global_load_lds staging, K-step 64, linear 128B rows,
//            both-sides XOR swizzle; detail z-split 8. Bit-identical K order.
// coarse: M=576,N=768,K=16384  detail(sel): M=256,N=768,K=4096  merge: M=1024,N=768,K=3072

__device__ __forceinline__ float gelu_f(float v){
    return 0.5f*v*(1.0f + erff(v*0.70710678118654752440f));
}
__device__ __forceinline__ unsigned short f2bf(float v){
    unsigned u = __float_as_uint(v);
    return (unsigned short)((u + 0x7FFFu + ((u>>16)&1u)) >> 16);   // RNE
}
__device__ __forceinline__ float bf2f(unsigned short h){
    return __uint_as_float(((unsigned)h)<<16);
}
__device__ __forceinline__ void split2(float v, unsigned short& hi, unsigned short& lo){
    hi = f2bf(v);
    lo = f2bf(v - bf2f(hi));
}

typedef short bf16x8 __attribute__((ext_vector_type(8)));
typedef float f32x4  __attribute__((ext_vector_type(4)));

// ---- BN scale/shift: out[0..63]=s1, [64..127]=sh1, [128..191]=s2, [192..255]=sh2
__global__ void bnprep_k(const float* g1,const float* b1,const float* m1,const float* v1,
                         const float* g2,const float* b2,const float* m2,const float* v2,
                         float* outp){
    int t = threadIdx.x;
    if (t < 64){
        float s = g1[t]/sqrtf(v1[t]+1e-5f);
        outp[t] = s; outp[64+t] = b1[t]-m1[t]*s;
        float s2 = g2[t]/sqrtf(v2[t]+1e-5f);
        outp[128+t] = s2; outp[192+t] = b2[t]-m2[t]*s2;
    }
}

// ---- conv2 weights -> split-2 bf16, n-major [64][576], k' = (kh*3+kw)*64 + ci
__global__ void w2prep_k(const float* __restrict__ w,
                         unsigned short* __restrict__ bhi, unsigned short* __restrict__ blo){
    int idx = blockIdx.x*256 + threadIdx.x;
    if (idx >= 36864) return;
    int n = idx/576, kp = idx - n*576;
    int t = kp>>6, ci = kp&63; int kh = t/3, kw = t - kh*3;
    float v = w[((n*64+ci)*3+kh)*3+kw];
    unsigned short hi,lo; split2(v,hi,lo);
    bhi[n*576+kp]=hi; blo[n*576+kp]=lo;
}

// ---- flat f32 -> bf16 convert
__global__ __launch_bounds__(256) void cvtbf16_k(const float* __restrict__ in,
                                                 unsigned short* __restrict__ out, int n){
    int i = blockIdx.x*256 + threadIdx.x;
    if (i < n) out[i] = f2bf(in[i]);
}

// ---- zero the 1-px border of padded f1 (386x386x64), hi+lo; run once
__global__ __launch_bounds__(256) void zpad_k(unsigned short* __restrict__ f1hi,
                                              unsigned short* __restrict__ f1lo){
    int idx = blockIdx.x*256 + threadIdx.x;
    if (idx >= 1540*8) return;
    int pi = idx>>3, c8 = (idx&7)*8;
    int p;
    if (pi < 386)       p = pi;                       // top row
    else if (pi < 772)  p = 385*386 + (pi-386);       // bottom row
    else if (pi < 1156) p = (pi-772+1)*386;           // left col rows 1..384
    else                p = (pi-1156+1)*386 + 385;    // right col rows 1..384
    float4 z = {0.f,0.f,0.f,0.f};
    *(float4*)(f1hi + (size_t)p*64 + c8) = z;
    *(float4*)(f1lo + (size_t)p*64 + c8) = z;
}

// ---- conv1 3->64 3x3 SAME + BN + GELU; padded (386x386) NHWC split-2 bf16 (one image)
// Coalesced halo staging: 306 floats [ci][kh][34]; compute reads broadcast from LDS.
// Block swizzle XCD-aligned with conv2's reader.
__global__ __launch_bounds__(256) void conv1_k(const float* __restrict__ x,
                                               const float* __restrict__ w,
                                               const float* __restrict__ bnp,
                                               unsigned short* __restrict__ f1hi,
                                               unsigned short* __restrict__ f1lo){
    __shared__ float ws[64*27];
    __shared__ float xr[9*34];
    __shared__ float s1[64], sh1[64];
    int tid = threadIdx.x;
    for (int i=tid;i<1728;i+=256) ws[i] = w[i];
    if (tid < 64){ s1[tid] = bnp[tid]; sh1[tid] = bnp[64+tid]; }
    int bid = blockIdx.x;
    int swb = (bid&7)*576 + (bid>>3);      // 4608 blocks, XCD-aligned
    int p0 = swb*32;
    int h0 = p0/384, x0 = p0 - h0*384;     // 32 | 384 -> row-uniform block
    for (int t=tid; t<306; t+=256){
        int ci = t/102, rem = t - ci*102;
        int kh = rem/34, col = rem - kh*34;
        int y = h0+kh-1, xx = x0+col-1;
        float v = 0.f;
        if ((unsigned)y<384u && (unsigned)xx<384u)
            v = x[ci*147456 + y*384 + xx];
        xr[(ci*3+kh)*34 + col] = v;
    }
    __syncthreads();
    int px = tid>>3, cg = tid&7;
    float a[8];
    #pragma unroll
    for (int u=0;u<8;u++) a[u]=0.f;
    #pragma unroll
    for (int ci=0;ci<3;ci++)
        #pragma unroll
        for (int kh=0;kh<3;kh++)
            #pragma unroll
            for (int kw=0;kw<3;kw++){
                const int j = (ci*3+kh)*3+kw;            // same j order as before
                float xv = xr[(ci*3+kh)*34 + px + kw];
                #pragma unroll
                for (int u=0;u<8;u++) a[u] += xv*ws[(cg*8+u)*27+j];
            }
    unsigned short hs[8], ls[8];
    #pragma unroll
    for (int u=0;u<8;u++){
        int co = cg*8+u;
        float v = gelu_f(a[u]*s1[co] + sh1[co]);
        split2(v, hs[u], ls[u]);
    }
    size_t off = ((size_t)(h0+1)*386 + (x0+px+1))*64 + cg*8;
    *(float4*)(f1hi + off) = *(float4*)hs;
    *(float4*)(f1lo + off) = *(float4*)ls;
}

// ---- conv2 via split-2 bf16 MFMA (LDS-staged via global_load_lds, 2 barriers/tap,
// 3 waves). Linear 64-short LDS rows; slot XOR swizzle applied to BOTH the global
// source address and the ds_read address (involution, rule #21). One image.
// Fused epilogue: Ac16 bf16 + per-(cell,row,ch) {sum,sumsq} partials.
__global__ __launch_bounds__(192) void conv2_mfma_k(
        const unsigned short* __restrict__ f1hi, const unsigned short* __restrict__ f1lo,
        const unsigned short* __restrict__ bhi,  const unsigned short* __restrict__ blo,
        const float* __restrict__ bnsc, const float* __restrict__ bnsh,
        unsigned short* __restrict__ Ac, float* __restrict__ parts){
    __shared__ __align__(16) unsigned short AhL[192*64], AlL[192*64];
    __shared__ __align__(16) unsigned short BhL[64*64],  BlL[64*64];
    const int tid = threadIdx.x;
    const int bid = blockIdx.x;
    const int swz = (bid&7)*96 + (bid>>3);     // 768 blocks, XCD-aligned with conv1
    const int bm = swz*192;
    const int y = bm/384, x0 = bm - y*384;     // x0 in {0,192}
    const int wv = tid>>6, lane = tid&63, lm = lane&15, q = lane>>4;

    // staging sources (per-thread constants; tap adds an offset)
    int aSrc[8];
    #pragma unroll
    for (int i=0;i<8;i++){
        int ch = tid + i*192;
        int pr = ch>>3, p8 = ch&7;
        aSrc[i] = (y*386 + x0 + pr)*64 + ((p8 ^ (pr&7))<<3);   // pad absorbs -1
    }
    int bSrc[3];
    #pragma unroll
    for (int i=0;i<3;i++){
        int ch = tid + i*192;
        int n = ch>>3, p8 = ch&7;
        bSrc[i] = n*576 + ((p8 ^ (n&7))<<3);
    }
    // ds_read byte addrs (swizzled), per-thread constants
    int aRd[4][2], bRd[4][2];
    #pragma unroll
    for (int mi=0;mi<4;mi++){
        int r = wv*64 + mi*16 + lm;
        #pragma unroll
        for (int h=0;h<2;h++)
            aRd[mi][h] = r*128 + (((h*4+q) ^ (r&7))<<4);
    }
    #pragma unroll
    for (int nj=0;nj<4;nj++){
        int r = nj*16 + lm;
        #pragma unroll
        for (int h=0;h<2;h++)
            bRd[nj][h] = r*128 + (((h*4+q) ^ (r&7))<<4);
    }

    f32x4 acc[4][4];
    #pragma unroll
    for (int i=0;i<4;i++)
        #pragma unroll
        for (int j=0;j<4;j++) acc[i][j] = (f32x4){0.f,0.f,0.f,0.f};

    for (int t9=0; t9<9; t9++){
        const int kh = t9/3, kw = t9 - kh*3;
        const int aoff = (kh*386 + kw)*64;
        const int boff = t9*64;
        #pragma unroll
        for (int i=0;i<8;i++){
            __builtin_amdgcn_global_load_lds(f1hi + aSrc[i] + aoff, &AhL[(tid+i*192)*8], 16, 0, 0);
            __builtin_amdgcn_global_load_lds(f1lo + aSrc[i] + aoff, &AlL[(tid+i*192)*8], 16, 0, 0);
        }
        #pragma unroll
        for (int i=0;i<3;i++){
            int ch = tid + i*192;
            if (ch < 512){   // wave-uniform: i=2 skips wave 2 entirely
                __builtin_amdgcn_global_load_lds(bhi + bSrc[i] + boff, &BhL[ch*8], 16, 0, 0);
                __builtin_amdgcn_global_load_lds(blo + bSrc[i] + boff, &BlL[ch*8], 16, 0, 0);
            }
        }
        __syncthreads();
        #pragma unroll
        for (int h=0; h<2; h++){
            bf16x8 ah[4], al[4], bh8[4], bl8[4];
            #pragma unroll
            for (int mi=0;mi<4;mi++){
                ah[mi] = *(const bf16x8*)((const char*)AhL + aRd[mi][h]);
                al[mi] = *(const bf16x8*)((const char*)AlL + aRd[mi][h]);
            }
            #pragma unroll
            for (int nj=0;nj<4;nj++){
                bh8[nj] = *(const bf16x8*)((const char*)BhL + bRd[nj][h]);
                bl8[nj] = *(const bf16x8*)((const char*)BlL + bRd[nj][h]);
            }
            #pragma unroll
            for (int mi=0;mi<4;mi++)
                #pragma unroll
                for (int nj=0;nj<4;nj++){
                    acc[mi][nj] = __builtin_amdgcn_mfma_f32_16x16x32_bf16(ah[mi], bh8[nj], acc[mi][nj], 0,0,0);
                    acc[mi][nj] = __builtin_amdgcn_mfma_f32_16x16x32_bf16(al[mi], bh8[nj], acc[mi][nj], 0,0,0);
                    acc[mi][nj] = __builtin_amdgcn_mfma_f32_16x16x32_bf16(ah[mi], bl8[nj], acc[mi][nj], 0,0,0);
                }
        }
        __syncthreads();
    }

    // ---- fused epilogue: gelu -> Ac16 bf16 + per-cell-row {sum,sumsq} partials
    const int gy = y>>4, py = y&15;
    #pragma unroll
    for (int mi=0;mi<4;mi++){
        const int xb = x0 + wv*64 + mi*16;          // 16-aligned pixel-col base
        const int cell = gy*24 + (xb>>4);
        unsigned short* acb = Ac + (size_t)cell*16384;
        float* pp = parts + (size_t)(cell*16 + py)*128;   // 64 ch * 2 floats
        #pragma unroll
        for (int nj=0;nj<4;nj++){
            const int n = nj*16 + lm;
            const float sc = bnsc[n], sh = bnsh[n];
            float g0 = gelu_f(acc[mi][nj][0]*sc + sh);
            float g1 = gelu_f(acc[mi][nj][1]*sc + sh);
            float g2 = gelu_f(acc[mi][nj][2]*sc + sh);
            float g3 = gelu_f(acc[mi][nj][3]*sc + sh);
            // Ac16: k = n*256 + py*16 + (q*4 + r), 8B store
            unsigned int u0 = (unsigned)f2bf(g0) | ((unsigned)f2bf(g1)<<16);
            unsigned int u1 = (unsigned)f2bf(g2) | ((unsigned)f2bf(g3)<<16);
            uint2 uu; uu.x = u0; uu.y = u1;
            *(uint2*)(acb + (size_t)n*256 + py*16 + q*4) = uu;
            // partial sum/sumsq over this 16-px cell-row slice
            float s  = ((g0+g1)+g2)+g3;
            float ss = ((g0*g0+g1*g1)+g2*g2)+g3*g3;
            s  += __shfl_xor(s,16);  s  += __shfl_xor(s,32);
            ss += __shfl_xor(ss,16); ss += __shfl_xor(ss,32);
            if (q==0){
                float2 v; v.x = s; v.y = ss;
                *(float2*)(pp + n*2) = v;
            }
        }
    }
}

// ---- per-cell score from partials: var = E[x^2]-E[x]^2 per ch, mean over ch
__global__ __launch_bounds__(64) void score_k(const float* __restrict__ parts,
                                              float* __restrict__ scores){
    const int cell = blockIdx.x;       // 0..575
    const int n = threadIdx.x;         // channel
    float s = 0.f, ss = 0.f;
    #pragma unroll
    for (int py=0;py<16;py++){
        float2 v = *(const float2*)(parts + (size_t)(cell*16+py)*128 + n*2);
        s += v.x; ss += v.y;
    }
    float mean = s*(1.f/256.f);
    float var  = ss*(1.f/256.f) - mean*mean;
    var += __shfl_down(var,32); var += __shfl_down(var,16);
    var += __shfl_down(var,8);  var += __shfl_down(var,4);
    var += __shfl_down(var,2);  var += __shfl_down(var,1);
    if (n==0) scores[cell] = var*(1.f/64.f);
}

// ---- generic bf16 MFMA GEMM v2: tile M=64 x N=128, 256 thr (4 waves), K-split z.
// Staging via global_load_lds(16); linear 128B LDS rows; both-sides XOR swizzle.
// K-step 64 (two 32-halves in original order -> bit-identical accumulation).
// MODE 0: coarse  A=Ac16 rows [576][16384]
// MODE 1: detail  A=Ac16 gathered: row=(topk[sel],dy,dx), k=c*64+qy*8+qx
// MODE 2: merge   A=dp16 rows [1024][3072]
template<int MODE, int KL, int MT>
__global__ __launch_bounds__(256) void gemm16_k(const unsigned short* __restrict__ A,
                                                const unsigned short* __restrict__ W,
                                                const int* __restrict__ topk,
                                                float* __restrict__ part){
    constexpr int KT = (MODE==0)?16384:(MODE==1)?4096:3072;   // W row length
    __shared__ __align__(16) unsigned short As[64*64];
    __shared__ __align__(16) unsigned short Bs[128*64];
    const int tid = threadIdx.x;
    const int nt = blockIdx.x, mt = blockIdx.y, z = blockIdx.z;
    const int m0 = mt*64, n0 = nt*128;
    const int wv = tid>>6, lane = tid&63;
    const int lm = lane&15, q = lane>>4;

    // staging: granule g = tid + it*256; row = g>>3, slot = g&7.
    // LDS dest is linear (g*16B); source k pre-XORed so LDS[row][slot] holds
    // logical[row][slot ^ (row&7)] — read side applies the same XOR.
    const int srow = tid>>3, sslot = tid&7;
    const int sx = (sslot ^ (srow&7))*8;          // logical k offset (shorts)
    size_t aSb[2];
    #pragma unroll
    for (int it=0;it<2;it++){
        int row = srow + it*32;                   // (row&7) == (srow&7)
        if (MODE==1){
            int t = m0 + row; int sel = t>>2, dd = t&3;
            int cell = topk[sel];
            aSb[it] = (size_t)cell*16384 + (dd>>1)*128 + (dd&1)*8 + sx*2;
        } else {
            aSb[it] = (size_t)(m0+row)*KT + sx;
        }
    }
    size_t bSb[4];
    #pragma unroll
    for (int it=0;it<4;it++)
        bSb[it] = (size_t)(n0 + srow + it*32)*KT + sx;

    // ds_read byte addrs (swizzled), per-thread constants
    int aRd[4][2], bRd[2][2];
    #pragma unroll
    for (int mi=0;mi<4;mi++){
        int r = mi*16 + lm;
        #pragma unroll
        for (int h=0;h<2;h++)
            aRd[mi][h] = r*128 + (((h*4+q) ^ (r&7))<<4);
    }
    #pragma unroll
    for (int nj=0;nj<2;nj++){
        int r = wv*32 + nj*16 + lm;
        #pragma unroll
        for (int h=0;h<2;h++)
            bRd[nj][h] = r*128 + (((h*4+q) ^ (r&7))<<4);
    }

    f32x4 acc[4][2];
    #pragma unroll
    for (int i=0;i<4;i++)
        #pragma unroll
        for (int j=0;j<2;j++)
            acc[i][j] = (f32x4){0.f,0.f,0.f,0.f};

    const int kb0 = z*KL;
    for (int kb = kb0; kb < kb0+KL; kb += 64){
        #pragma unroll
        for (int it=0;it<2;it++){
            const unsigned short* src = (MODE==1) ? (A + aSb[it] + (size_t)(kb>>6)*256)
                                                  : (A + aSb[it] + kb);
            __builtin_amdgcn_global_load_lds(src, &As[(tid + it*256)*8], 16, 0, 0);
        }
        #pragma unroll
        for (int it=0;it<4;it++)
            __builtin_amdgcn_global_load_lds(W + bSb[it] + kb, &Bs[(tid + it*256)*8], 16, 0, 0);
        __syncthreads();
        #pragma unroll
        for (int h=0;h<2;h++){
            bf16x8 af[4], bb[2];
            #pragma unroll
            for (int mi=0;mi<4;mi++) af[mi] = *(const bf16x8*)((const char*)As + aRd[mi][h]);
            #pragma unroll
            for (int nj=0;nj<2;nj++) bb[nj] = *(const bf16x8*)((const char*)Bs + bRd[nj][h]);
            #pragma unroll
            for (int mi=0;mi<4;mi++)
                #pragma unroll
                for (int nj=0;nj<2;nj++)
                    acc[mi][nj] = __builtin_amdgcn_mfma_f32_16x16x32_bf16(af[mi], bb[nj], acc[mi][nj], 0,0,0);
        }
        __syncthreads();
    }

    float* pz = part + (size_t)z*MT*768;
    #pragma unroll
    for (int mi=0;mi<4;mi++)
        #pragma unroll
        for (int nj=0;nj<2;nj++)
            #pragma unroll
            for (int r=0;r<4;r++){
                int m = m0 + mi*16 + q*4 + r;
                int n = n0 + wv*32 + nj*16 + lm;
                pz[m*768 + n] = acc[mi][nj][r];
            }
}

// ---- sum K-split partials + bias -> f32
__global__ __launch_bounds__(256) void reduce_k(const float* __restrict__ partials,
                                                const float* __restrict__ bias,
                                                float* __restrict__ outp,
                                                int MTOT, int NSPLIT){
    int idx = blockIdx.x*256 + threadIdx.x;
    int col = idx % 768;
    float s = bias[col];
    for (int i=0;i<NSPLIT;i++) s += partials[(size_t)i*MTOT*768 + idx];
    outp[idx] = s;
}

// ---- sum K-split partials + bias -> bf16
__global__ __launch_bounds__(256) void reduce16_k(const float* __restrict__ partials,
                                                  const float* __restrict__ bias,
                                                  unsigned short* __restrict__ outp,
                                                  int MTOT, int NSPLIT){
    int idx = blockIdx.x*256 + threadIdx.x;
    int col = idx % 768;
    float s = bias[col];
    for (int i=0;i<NSPLIT;i++) s += partials[(size_t)i*MTOT*768 + idx];
    outp[idx] = f2bf(s);
}

// ---- top-64 of 576 via rank counting; jax tie-break (lower idx first), one shot
__global__ __launch_bounds__(576) void topk_k(const float* __restrict__ scores,
                                              int* __restrict__ topk,
                                              float* __restrict__ outf){
    __shared__ float s[576];
    int t = threadIdx.x;
    s[t] = scores[t];
    __syncthreads();
    float v = s[t];
    int cnt = 0;
    for (int j=0;j<576;j++){
        float u = s[j];
        cnt += (u > v) || (u == v && j < t);
    }
    if (cnt < 64){ topk[cnt] = t; outf[cnt] = (float)t; }
}

extern "C" void kernel_launch(void* const* d_in, const int* in_sizes, int n_in,
                              void* d_out, int out_size, void* d_ws, size_t ws_size,
                              hipStream_t stream){
    const float* x       = (const float*)d_in[0];
    const float* conv1_w = (const float*)d_in[1];
    const float* bn1_g   = (const float*)d_in[2];
    const float* bn1_b   = (const float*)d_in[3];
    const float* bn1_m   = (const float*)d_in[4];
    const float* bn1_v   = (const float*)d_in[5];
    const float* conv2_w = (const float*)d_in[6];
    const float* bn2_g   = (const float*)d_in[7];
    const float* bn2_b   = (const float*)d_in[8];
    const float* bn2_m   = (const float*)d_in[9];
    const float* bn2_v   = (const float*)d_in[10];
    const float* coarse_w= (const float*)d_in[11];
    const float* coarse_b= (const float*)d_in[12];
    const float* detail_w= (const float*)d_in[13];
    const float* detail_b= (const float*)d_in[14];
    const float* merge_w = (const float*)d_in[15];
    const float* merge_b = (const float*)d_in[16];
    float* out = (float*)d_out;

    // ---- workspace layout (float units); ~152 MB ----
    float* wsp  = (float*)d_ws;
    unsigned short* f1hi = (unsigned short*)wsp;         // 9,535,744 bf16 (386*386*64)
    unsigned short* f1lo = f1hi + 9535744;               // 9,535,744 bf16
    float* parts = wsp + 9535744;                        // 1,179,648 f32 (slot 9.4M)
    float* bnp  = parts + 9437184;                       // 256
    float* scores = bnp + 256;                           // 9,216
    int*   topk = (int*)(scores + 9216);                 // 1,024
    unsigned short* B2hi = (unsigned short*)(topk + 1024);   // 36,864 bf16
    unsigned short* B2lo = B2hi + 36864;                     // 36,864 bf16
    unsigned short* Wc16 = B2lo + 36864;                     // 12,582,912 bf16
    unsigned short* Wd16 = Wc16 + 12582912;                  // 3,145,728 bf16
    unsigned short* Wm16 = Wd16 + 3145728;                   // 2,359,296 bf16
    unsigned short* Ac16 = Wm16 + 2359296;                   // 9,437,184 bf16
    unsigned short* dp16 = Ac16 + 9437184;                   // 3,145,728 bf16
    float* part = (float*)(dp16 + 3145728);                  // 3,538,944 f32

    if (ws_size < (size_t)171000000) return;   // graceful fail if ws too small

    const int DETAIL_OFF = 16*576*768;            // 7077888
    const int IDX_OFF    = DETAIL_OFF + 16*64*768;// 7864320

    bnprep_k<<<1,64,0,stream>>>(bn1_g,bn1_b,bn1_m,bn1_v, bn2_g,bn2_b,bn2_m,bn2_v, bnp);
    w2prep_k<<<144,256,0,stream>>>(conv2_w, B2hi, B2lo);
    cvtbf16_k<<<49152,256,0,stream>>>(coarse_w, Wc16, 12582912);
    cvtbf16_k<<<12288,256,0,stream>>>(detail_w, Wd16, 3145728);
    cvtbf16_k<<<9216,256,0,stream>>>(merge_w,  Wm16, 2359296);
    zpad_k<<<49,256,0,stream>>>(f1hi, f1lo);     // once: borders stay zero

    for (int b = 0; b < 16; b++){
        conv1_k<<<4608,256,0,stream>>>(x + (size_t)b*442368, conv1_w, bnp, f1hi, f1lo);
        conv2_mfma_k<<<768,192,0,stream>>>(f1hi, f1lo, B2hi, B2lo, bnp+128, bnp+192,
                                           Ac16, parts);
        score_k<<<576,64,0,stream>>>(parts, scores + b*576);
        topk_k<<<1,576,0,stream>>>(scores + b*576, topk + b*64, out + IDX_OFF + b*64);
        // coarse tokens
        gemm16_k<0,2048,576><<<dim3(6,9,8),256,0,stream>>>(Ac16, Wc16, nullptr, part);
        reduce_k<<<1728,256,0,stream>>>(part, coarse_b, out + (size_t)b*442368, 576, 8);
        // detail tokens (selected) — A gathered from Ac16
        gemm16_k<1,512,256><<<dim3(6,4,8),256,0,stream>>>(Ac16, Wd16, topk + b*64, part);
        reduce16_k<<<768,256,0,stream>>>(part, detail_b, dp16 + (size_t)b*196608, 256, 8);
    }

    // merge over all batches: M=1024, K=3072
    gemm16_k<2,768,1024><<<dim3(6,16,4),256,0,stream>>>(dp16, Wm16, nullptr, part);
    reduce_k<<<3072,256,0,stream>>>(part, merge_b, out + DETAIL_OFF, 1024, 4);
}